// Round 4
// baseline (128.500 us; speedup 1.0000x reference)
//
#include <hip/hip_runtime.h>

#define NV 13824   // 24*24*24 voxels per batch
#define CCH 64     // channels
#define NB 2       // batch

// ---------------------------------------------------------------------------
// Kernel 1 (v3): q/k/v projections.
// Block = 512 threads = 64 rows (voxels) x 8 output-parts (8 ch x 3 tensors
// per thread). part = t>>6 is wave-uniform -> LDS weight reads broadcast.
// All outputs computed to registers first; the 16KB output-transpose stage
// is ALIASED over the Wq LDS region -> total LDS 48.75KB. Stores are
// 512-lane x float4 = 8KB contiguous. Grid now runs 3.4 waves/SIMD
// (round-3 version was 1.7 waves/SIMD and sync-bound).
// ---------------------------------------------------------------------------
__global__ __launch_bounds__(512) void qkv_kernel(
    const float* __restrict__ x,
    const float* __restrict__ Wq, const float* __restrict__ bq,
    const float* __restrict__ Wk, const float* __restrict__ bk,
    const float* __restrict__ Wv, const float* __restrict__ bv,
    float* __restrict__ qo, float* __restrict__ ko, float* __restrict__ vo)
{
    __shared__ float sW[3 * 4096];   // [0..4095]=Wq (reused as stage), Wk, Wv
    __shared__ float sB[3 * 64];

    const int t = threadIdx.x;       // 0..511

    // stage weights (3 x 16KB) + biases into LDS, float4-vectorized
    {
        const float4* s0 = (const float4*)Wq;
        const float4* s1 = (const float4*)Wk;
        const float4* s2 = (const float4*)Wv;
        float4* dd = (float4*)sW;
        for (int i = t; i < 1024; i += 512) {
            dd[i]        = s0[i];
            dd[1024 + i] = s1[i];
            dd[2048 + i] = s2[i];
        }
        if (t < 64) { sB[t] = bq[t]; sB[64 + t] = bk[t]; sB[128 + t] = bv[t]; }
    }
    __syncthreads();

    const int row  = t & 63;
    const int part = t >> 6;                // 0..7, uniform within wave
    const int gr   = blockIdx.x * 64 + row; // global row 0..27647
    const int b    = gr / NV;
    const int n    = gr - b * NV;

    const float* xb = x + (size_t)b * CCH * NV + n;

    // load this row's 64 input channels (coalesced: lanes = consecutive n)
    float4 xr[16];
    #pragma unroll
    for (int c4 = 0; c4 < 16; ++c4) {
        xr[c4].x = xb[(size_t)(c4 * 4 + 0) * NV];
        xr[c4].y = xb[(size_t)(c4 * 4 + 1) * NV];
        xr[c4].z = xb[(size_t)(c4 * 4 + 2) * NV];
        xr[c4].w = xb[(size_t)(c4 * 4 + 3) * NV];
    }

    // compute ALL outputs to registers (8 ch x 3 tensors = 6 float4) BEFORE
    // the stage buffer (aliased over Wq) is touched
    float4 ot[3][2];
    #pragma unroll
    for (int m = 0; m < 3; ++m) {
        const float4* wm = (const float4*)(sW + m * 4096) + (part * 8) * 16;
        const float*  bm = sB + m * 64 + part * 8;
        #pragma unroll
        for (int g = 0; g < 2; ++g) {
            float a0 = 0.f, a1 = 0.f, a2 = 0.f, a3 = 0.f;
            #pragma unroll
            for (int c4 = 0; c4 < 16; ++c4) {
                const float4 xv = xr[c4];
                const float4 w0 = wm[(g * 4 + 0) * 16 + c4];  // wave-uniform
                a0 += xv.x * w0.x + xv.y * w0.y + xv.z * w0.z + xv.w * w0.w;
                const float4 w1 = wm[(g * 4 + 1) * 16 + c4];
                a1 += xv.x * w1.x + xv.y * w1.y + xv.z * w1.z + xv.w * w1.w;
                const float4 w2 = wm[(g * 4 + 2) * 16 + c4];
                a2 += xv.x * w2.x + xv.y * w2.y + xv.z * w2.z + xv.w * w2.w;
                const float4 w3 = wm[(g * 4 + 3) * 16 + c4];
                a3 += xv.x * w3.x + xv.y * w3.y + xv.z * w3.z + xv.w * w3.w;
            }
            ot[m][g] = make_float4(a0 + bm[g * 4 + 0], a1 + bm[g * 4 + 1],
                                   a2 + bm[g * 4 + 2], a3 + bm[g * 4 + 3]);
        }
    }

    // bounce each tensor through the stage (aliased over Wq region),
    // then store fully-coalesced (512 lanes x 16B = 8KB per instruction)
    float4* sStage = (float4*)sW;   // 1024 float4 = 16KB
    #pragma unroll
    for (int m = 0; m < 3; ++m) {
        float* outp = (m == 0) ? qo : ((m == 1) ? ko : vo);
        __syncthreads();   // stage free (weights consumed / prev readers done)
        #pragma unroll
        for (int g = 0; g < 2; ++g) {
            const int c = part * 2 + g;                    // float4-col 0..15
            sStage[row * 16 + ((c ^ row) & 15)] = ot[m][g]; // XOR swizzle
        }
        __syncthreads();
        float4* gdst = (float4*)(outp + (size_t)blockIdx.x * 4096);
        #pragma unroll
        for (int s2 = 0; s2 < 2; ++s2) {
            const int j  = s2 * 512 + t;     // float4 index 0..1023
            const int rr = j >> 4;
            const int cc = j & 15;
            gdst[j] = sStage[rr * 16 + ((cc ^ rr) & 15)];
        }
    }
}

// ---------------------------------------------------------------------------
// Kernel 2: local attention, thread = (voxel, head). UNCHANGED from round 2.
// ---------------------------------------------------------------------------
__global__ __launch_bounds__(256) void attn_kernel(
    const float* __restrict__ x,
    const float* __restrict__ qw,
    const float* __restrict__ kw,
    const float* __restrict__ vw,
    float* __restrict__ out)
{
    const int t    = threadIdx.x;
    const int vb   = t >> 2;       // voxel within block, 0..63
    const int head = t & 3;        // 0..3
    const int gr   = blockIdx.x * 64 + vb;
    const int b    = gr / NV;
    const int n    = gr - b * NV;
    const int d    = n / 576;
    const int rem  = n - d * 576;
    const int r    = rem / 24;
    const int w    = rem - r * 24;

    // neighbor element indices (-1 if out of bounds), torch-unfold order
    int nidx[27];
    #pragma unroll
    for (int i3 = 0; i3 < 3; ++i3)
    #pragma unroll
    for (int j3 = 0; j3 < 3; ++j3)
    #pragma unroll
    for (int l3 = 0; l3 < 3; ++l3) {
        const int dd = d + i3 - 1;
        const int rr = r + j3 - 1;
        const int ww = w + l3 - 1;
        const bool ok = ((unsigned)dd < 24u) & ((unsigned)rr < 24u) & ((unsigned)ww < 24u);
        nidx[(i3 * 3 + j3) * 3 + l3] = ok ? ((dd * 24 + rr) * 24 + ww) : -1;
    }

    // load q fragment (16 floats) and pre-scale by hd^-0.5 = 0.25
    const float4* qp = (const float4*)(qw + (size_t)gr * 64 + head * 16);
    float4 q0 = qp[0], q1 = qp[1], q2 = qp[2], q3 = qp[3];
    const float s = 0.25f;
    q0.x *= s; q0.y *= s; q0.z *= s; q0.w *= s;
    q1.x *= s; q1.y *= s; q1.z *= s; q1.w *= s;
    q2.x *= s; q2.y *= s; q2.z *= s; q2.w *= s;
    q3.x *= s; q3.y *= s; q3.z *= s; q3.w *= s;

    const float* kbase = kw + (size_t)b * NV * 64 + head * 16;

    float logit[27];
    #pragma unroll
    for (int j = 0; j < 27; ++j) {
        float a = 0.f;
        if (nidx[j] >= 0) {
            const float4* kp = (const float4*)(kbase + (size_t)nidx[j] * 64);
            const float4 k0 = kp[0], k1 = kp[1], k2 = kp[2], k3 = kp[3];
            a  = q0.x * k0.x + q0.y * k0.y + q0.z * k0.z + q0.w * k0.w;
            a += q1.x * k1.x + q1.y * k1.y + q1.z * k1.z + q1.w * k1.w;
            a += q2.x * k2.x + q2.y * k2.y + q2.z * k2.z + q2.w * k2.w;
            a += q3.x * k3.x + q3.y * k3.y + q3.z * k3.z + q3.w * k3.w;
        }
        logit[j] = a;   // OOB -> 0, still participates in softmax
    }

    float m = logit[0];
    #pragma unroll
    for (int j = 1; j < 27; ++j) m = fmaxf(m, logit[j]);
    float ssum = 0.f;
    #pragma unroll
    for (int j = 0; j < 27; ++j) {
        const float e = __expf(logit[j] - m);
        logit[j] = e;
        ssum += e;
    }
    const float inv = 1.f / ssum;

    float a00=0.f,a01=0.f,a02=0.f,a03=0.f, a10=0.f,a11=0.f,a12=0.f,a13=0.f;
    float a20=0.f,a21=0.f,a22=0.f,a23=0.f, a30=0.f,a31=0.f,a32=0.f,a33=0.f;
    const float* vbase = vw + (size_t)b * NV * 64 + head * 16;
    #pragma unroll
    for (int j = 0; j < 27; ++j) {
        if (nidx[j] >= 0) {
            const float p = logit[j];
            const float4* vp = (const float4*)(vbase + (size_t)nidx[j] * 64);
            const float4 v0 = vp[0], v1 = vp[1], v2 = vp[2], v3 = vp[3];
            a00 += p * v0.x; a01 += p * v0.y; a02 += p * v0.z; a03 += p * v0.w;
            a10 += p * v1.x; a11 += p * v1.y; a12 += p * v1.z; a13 += p * v1.w;
            a20 += p * v2.x; a21 += p * v2.y; a22 += p * v2.z; a23 += p * v2.w;
            a30 += p * v3.x; a31 += p * v3.y; a32 += p * v3.z; a33 += p * v3.w;
        }
    }

    // residual add + channel-major store
    const size_t cb = (size_t)b * CCH * NV + (size_t)(head * 16) * NV + n;
    const float* xb = x + cb;
    float* ob = out + cb;
    float av[16] = {a00,a01,a02,a03,a10,a11,a12,a13,a20,a21,a22,a23,a30,a31,a32,a33};
    #pragma unroll
    for (int i = 0; i < 16; ++i) {
        ob[(size_t)i * NV] = xb[(size_t)i * NV] + av[i] * inv;
    }
}

// ---------------------------------------------------------------------------
extern "C" void kernel_launch(void* const* d_in, const int* in_sizes, int n_in,
                              void* d_out, int out_size, void* d_ws, size_t ws_size,
                              hipStream_t stream) {
    const float* x  = (const float*)d_in[0];
    // d_in[1] = cemb, unused by the reference forward
    const float* Wq = (const float*)d_in[2];
    const float* bq = (const float*)d_in[3];
    const float* Wk = (const float*)d_in[4];
    const float* bk = (const float*)d_in[5];
    const float* Wv = (const float*)d_in[6];
    const float* bv = (const float*)d_in[7];
    float* out = (float*)d_out;

    float* ws = (float*)d_ws;
    const size_t RC = (size_t)NB * NV * CCH;   // 1,769,472 floats per tensor
    float* q = ws;
    float* k = ws + RC;
    float* v = ws + 2 * RC;

    const int nrows = NB * NV;                  // 27648
    const int blocks = nrows / 64;              // 432

    qkv_kernel<<<blocks, 512, 0, stream>>>(x, Wq, bq, Wk, bk, Wv, bv, q, k, v);
    attn_kernel<<<blocks, 256, 0, stream>>>(x, q, k, v, out);
}

// Round 5
// 114.329 us; speedup vs baseline: 1.1240x; 1.1240x over previous
//
#include <hip/hip_runtime.h>

#define NV 13824   // 24*24*24 voxels per batch
#define CCH 64     // channels
#define NB 2       // batch

// ---------------------------------------------------------------------------
// Kernel 1 (v4): q/k/v projections as a register-tiled GEMM.
// C[27648 x 192] = X^T[27648 x 64] * W^T[64 x 192] (+bias), computed as
// 3 tensors of N=64. Block = 256 threads, tile M=128 rows, full K=64.
// Thread tile = 4 rows x 8 cols per tensor (acc as float4 over rows).
// LDS: sX[64][128] (32KB, == global layout, trivial stage) +
//      sWT[3][64][64] (48KB, transposed via conflict-free writes) = 80KB
// -> 2 blocks/CU. Each ds_read_b128 feeds 32 FMAs (v3's broadcast scheme
// fed 4 -> was LDS-instruction-bound at ~26us).
// ---------------------------------------------------------------------------
__global__ __launch_bounds__(256) void qkv_kernel(
    const float* __restrict__ x,
    const float* __restrict__ Wq, const float* __restrict__ bq,
    const float* __restrict__ Wk, const float* __restrict__ bk,
    const float* __restrict__ Wv, const float* __restrict__ bv,
    float* __restrict__ qo, float* __restrict__ ko, float* __restrict__ vo)
{
    __shared__ float sX[64 * 128];        // [k][row], 32KB
    __shared__ float sWT[3 * 64 * 64];    // [m][k][o], 48KB

    const int t  = threadIdx.x;
    const int n0 = blockIdx.x * 128;      // 128 | NV -> no batch straddle
    const int b  = n0 / NV;
    const int nn = n0 - b * NV;

    // stage X tile: LDS [k][row] == global [c][n] layout -> linear float4 copy
    {
        const float* xb = x + (size_t)b * CCH * NV + nn;
        float4* dst = (float4*)sX;
        #pragma unroll
        for (int it = 0; it < 8; ++it) {
            const int i = it * 256 + t;         // float4 idx 0..2047
            const int c = i >> 5;
            const int f = i & 31;
            dst[i] = *(const float4*)(xb + (size_t)c * NV + f * 4);
        }
    }
    // stage W transposed: lane o = t&63, k-chunk = t>>6 (conflict-free writes)
    {
        const int o  = t & 63;
        const int kk = t >> 6;
        const float* const Ws[3] = {Wq, Wk, Wv};
        #pragma unroll
        for (int m = 0; m < 3; ++m) {
            const float* wm = Ws[m] + o * 64 + kk * 16;
            float* dd = sWT + m * 4096 + o;
            #pragma unroll
            for (int k2 = 0; k2 < 16; ++k2)
                dd[(kk * 16 + k2) * 64] = wm[k2];
        }
    }
    __syncthreads();

    const int c0 = (t & 7) * 8;        // col base (8 cols)
    const int r0 = (t >> 3) * 4;       // row base (4 rows)

    float4 acc[3][8];
    #pragma unroll
    for (int m = 0; m < 3; ++m)
        #pragma unroll
        for (int c = 0; c < 8; ++c)
            acc[m][c] = make_float4(0.f, 0.f, 0.f, 0.f);

#define QKV_FMA(A, S) { (A).x += a.x*(S); (A).y += a.y*(S); (A).z += a.z*(S); (A).w += a.w*(S); }

    #pragma unroll 4
    for (int k = 0; k < 64; ++k) {
        const float4 a = *(const float4*)(sX + k * 128 + r0);
        #pragma unroll
        for (int m = 0; m < 3; ++m) {
            const float* wrow = sWT + m * 4096 + k * 64 + c0;
            const float4 b0 = *(const float4*)(wrow);
            const float4 b1 = *(const float4*)(wrow + 4);
            QKV_FMA(acc[m][0], b0.x) QKV_FMA(acc[m][1], b0.y)
            QKV_FMA(acc[m][2], b0.z) QKV_FMA(acc[m][3], b0.w)
            QKV_FMA(acc[m][4], b1.x) QKV_FMA(acc[m][5], b1.y)
            QKV_FMA(acc[m][6], b1.z) QKV_FMA(acc[m][7], b1.w)
        }
    }
#undef QKV_FMA

    // epilogue: bias + store. Per thread: 4 rows x (2 float4) per tensor.
    float* const outs[3] = {qo, ko, vo};
    const float* const bs[3] = {bq, bk, bv};
    #pragma unroll
    for (int m = 0; m < 3; ++m) {
        const float4 bb0 = *(const float4*)(bs[m] + c0);
        const float4 bb1 = *(const float4*)(bs[m] + c0 + 4);
        float* ob = outs[m] + (size_t)(n0 + r0) * 64 + c0;
#define QKV_ROW(RR, F) { \
        float4 o0 = make_float4(acc[m][0].F + bb0.x, acc[m][1].F + bb0.y, \
                                acc[m][2].F + bb0.z, acc[m][3].F + bb0.w); \
        float4 o1 = make_float4(acc[m][4].F + bb1.x, acc[m][5].F + bb1.y, \
                                acc[m][6].F + bb1.z, acc[m][7].F + bb1.w); \
        *(float4*)(ob + (size_t)(RR) * 64)     = o0; \
        *(float4*)(ob + (size_t)(RR) * 64 + 4) = o1; }
        QKV_ROW(0, x) QKV_ROW(1, y) QKV_ROW(2, z) QKV_ROW(3, w)
#undef QKV_ROW
    }
}

// ---------------------------------------------------------------------------
// Kernel 2 (v2): local attention, thread = (voxel, head, dim-half).
// Splitting each head over 2 lanes halves the gather chain (54 vs 108 loads)
// and doubles wave count (3.4/SIMD). Partial qk-dots combined via
// __shfl_xor(.,1); softmax computed redundantly on both halves.
// OOB neighbors: logit = 0 participates in softmax (zero-padded k), v = 0.
// ---------------------------------------------------------------------------
__global__ __launch_bounds__(256) void attn_kernel(
    const float* __restrict__ x,
    const float* __restrict__ qw,
    const float* __restrict__ kw,
    const float* __restrict__ vw,
    float* __restrict__ out)
{
    const int t    = threadIdx.x;
    const int half = t & 1;
    const int head = (t >> 1) & 3;
    const int vb   = t >> 3;            // 0..31 voxels per block
    const int gr   = blockIdx.x * 32 + vb;
    const int b    = gr / NV;
    const int n    = gr - b * NV;
    const int d    = n / 576;
    const int rem  = n - d * 576;
    const int r    = rem / 24;
    const int w    = rem - r * 24;

    // neighbor element indices (-1 if out of bounds), torch-unfold order
    int nidx[27];
    #pragma unroll
    for (int i3 = 0; i3 < 3; ++i3)
    #pragma unroll
    for (int j3 = 0; j3 < 3; ++j3)
    #pragma unroll
    for (int l3 = 0; l3 < 3; ++l3) {
        const int dd = d + i3 - 1;
        const int rr = r + j3 - 1;
        const int ww = w + l3 - 1;
        const bool ok = ((unsigned)dd < 24u) & ((unsigned)rr < 24u) & ((unsigned)ww < 24u);
        nidx[(i3 * 3 + j3) * 3 + l3] = ok ? ((dd * 24 + rr) * 24 + ww) : -1;
    }

    const int coff = head * 16 + half * 8;   // this lane's 8 channels

    // q fragment (8 floats), pre-scaled by hd^-0.5 = 0.25
    const float4* qp = (const float4*)(qw + (size_t)gr * 64 + coff);
    float4 q0 = qp[0], q1 = qp[1];
    const float s = 0.25f;
    q0.x *= s; q0.y *= s; q0.z *= s; q0.w *= s;
    q1.x *= s; q1.y *= s; q1.z *= s; q1.w *= s;

    const float* kbase = kw + (size_t)b * NV * 64 + coff;

    float logit[27];
    #pragma unroll
    for (int j = 0; j < 27; ++j) {
        float a = 0.f;
        if (nidx[j] >= 0) {
            const float4* kp = (const float4*)(kbase + (size_t)nidx[j] * 64);
            const float4 k0 = kp[0], k1 = kp[1];
            a  = q0.x * k0.x + q0.y * k0.y + q0.z * k0.z + q0.w * k0.w;
            a += q1.x * k1.x + q1.y * k1.y + q1.z * k1.z + q1.w * k1.w;
        }
        a += __shfl_xor(a, 1, 64);   // combine the two 8-dim halves
        logit[j] = a;                 // OOB -> 0, still in softmax
    }

    float m = logit[0];
    #pragma unroll
    for (int j = 1; j < 27; ++j) m = fmaxf(m, logit[j]);
    float ssum = 0.f;
    #pragma unroll
    for (int j = 0; j < 27; ++j) {
        const float e = __expf(logit[j] - m);
        logit[j] = e;
        ssum += e;
    }
    const float inv = 1.f / ssum;

    float a0=0.f,a1=0.f,a2=0.f,a3=0.f,a4=0.f,a5=0.f,a6=0.f,a7=0.f;
    const float* vbase = vw + (size_t)b * NV * 64 + coff;
    #pragma unroll
    for (int j = 0; j < 27; ++j) {
        if (nidx[j] >= 0) {
            const float p = logit[j];
            const float4* vp = (const float4*)(vbase + (size_t)nidx[j] * 64);
            const float4 v0 = vp[0], v1 = vp[1];
            a0 += p * v0.x; a1 += p * v0.y; a2 += p * v0.z; a3 += p * v0.w;
            a4 += p * v1.x; a5 += p * v1.y; a6 += p * v1.z; a7 += p * v1.w;
        }
    }

    // residual add + channel-major store (8 channels, stride NV)
    const size_t cb = (size_t)b * CCH * NV + (size_t)coff * NV + n;
    const float* xb = x + cb;
    float* ob = out + cb;
    float av[8] = {a0,a1,a2,a3,a4,a5,a6,a7};
    #pragma unroll
    for (int i = 0; i < 8; ++i) {
        ob[(size_t)i * NV] = xb[(size_t)i * NV] + av[i] * inv;
    }
}

// ---------------------------------------------------------------------------
extern "C" void kernel_launch(void* const* d_in, const int* in_sizes, int n_in,
                              void* d_out, int out_size, void* d_ws, size_t ws_size,
                              hipStream_t stream) {
    const float* x  = (const float*)d_in[0];
    // d_in[1] = cemb, unused by the reference forward
    const float* Wq = (const float*)d_in[2];
    const float* bq = (const float*)d_in[3];
    const float* Wk = (const float*)d_in[4];
    const float* bk = (const float*)d_in[5];
    const float* Wv = (const float*)d_in[6];
    const float* bv = (const float*)d_in[7];
    float* out = (float*)d_out;

    float* ws = (float*)d_ws;
    const size_t RC = (size_t)NB * NV * CCH;   // 1,769,472 floats per tensor
    float* q = ws;
    float* k = ws + RC;
    float* v = ws + 2 * RC;

    const int nrows = NB * NV;                  // 27648

    qkv_kernel<<<nrows / 128, 256, 0, stream>>>(x, Wq, bq, Wk, bk, Wv, bv, q, k, v);
    attn_kernel<<<nrows / 32, 256, 0, stream>>>(x, q, k, v, out);
}